// Round 1
// baseline (2372.867 us; speedup 1.0000x reference)
//
#include <hip/hip_runtime.h>

#define N_NODES 50000
#define N_EDGES 800000
#define LATENT 32
#define STEPS 10
#define NEG_SLOPE 0.01f
#define LN_EPS 1e-5f

__device__ __forceinline__ float leaky(float x) {
    return x >= 0.0f ? x : NEG_SLOPE * x;
}

__device__ __forceinline__ float4 f4fma(float a, float4 b, float4 c) {
    c.x += a * b.x; c.y += a * b.y; c.z += a * b.z; c.w += a * b.w;
    return c;
}

// ---------------- encoders ----------------

__global__ void encode_nodes_kernel(const float* __restrict__ x,
                                    const float* __restrict__ W,  // [6][32]
                                    const float* __restrict__ b,  // [32]
                                    float* __restrict__ h) {
    __shared__ __align__(16) float Ws[6 * 32];
    __shared__ __align__(16) float bs[32];
    int tid = threadIdx.x;
    if (tid < 192) Ws[tid] = W[tid];
    if (tid < 32) bs[tid] = b[tid];
    __syncthreads();
    int n = blockIdx.x * blockDim.x + tid;
    if (n >= N_NODES) return;
    float xv[6];
#pragma unroll
    for (int k = 0; k < 6; k++) xv[k] = x[(size_t)n * 6 + k];
    float4 acc[8];
#pragma unroll
    for (int q = 0; q < 8; q++) acc[q] = *(const float4*)&bs[q * 4];
#pragma unroll
    for (int k = 0; k < 6; k++) {
#pragma unroll
        for (int q = 0; q < 8; q++) {
            float4 w = *(const float4*)&Ws[k * 32 + q * 4];
            acc[q] = f4fma(xv[k], w, acc[q]);
        }
    }
#pragma unroll
    for (int q = 0; q < 8; q++) {
        float4 o = acc[q];
        o.x = leaky(o.x); o.y = leaky(o.y); o.z = leaky(o.z); o.w = leaky(o.w);
        *(float4*)&h[(size_t)n * 32 + q * 4] = o;
    }
}

__global__ void encode_edges_kernel(const float* __restrict__ ea,
                                    const float* __restrict__ W,  // [3][32]
                                    const float* __restrict__ b,  // [32]
                                    float* __restrict__ e) {
    __shared__ __align__(16) float Ws[3 * 32];
    __shared__ __align__(16) float bs[32];
    int tid = threadIdx.x;
    if (tid < 96) Ws[tid] = W[tid];
    if (tid < 32) bs[tid] = b[tid];
    __syncthreads();
    int i = blockIdx.x * blockDim.x + tid;
    if (i >= N_EDGES) return;
    float xv[3];
#pragma unroll
    for (int k = 0; k < 3; k++) xv[k] = ea[(size_t)i * 3 + k];
    float4 acc[8];
#pragma unroll
    for (int q = 0; q < 8; q++) acc[q] = *(const float4*)&bs[q * 4];
#pragma unroll
    for (int k = 0; k < 3; k++) {
#pragma unroll
        for (int q = 0; q < 8; q++) {
            float4 w = *(const float4*)&Ws[k * 32 + q * 4];
            acc[q] = f4fma(xv[k], w, acc[q]);
        }
    }
#pragma unroll
    for (int q = 0; q < 8; q++) {
        float4 o = acc[q];
        o.x = leaky(o.x); o.y = leaky(o.y); o.z = leaky(o.z); o.w = leaky(o.w);
        *(float4*)&e[(size_t)i * 32 + q * 4] = o;
    }
}

// ---------------- CSR build (once per launch) ----------------

__global__ void count_kernel(const int* __restrict__ recv, int* __restrict__ cnt) {
    int i = blockIdx.x * blockDim.x + threadIdx.x;
    if (i < N_EDGES) atomicAdd(&cnt[recv[i]], 1);
}

__global__ void scan_kernel(const int* __restrict__ cnt,
                            int* __restrict__ row_start,
                            int* __restrict__ cursor,
                            float* __restrict__ inv_cnt, int n) {
    __shared__ int sdata[1024];
    __shared__ int s_carry;
    int tid = threadIdx.x;
    if (tid == 0) s_carry = 0;
    __syncthreads();
    for (int base = 0; base < n; base += 1024) {
        int i = base + tid;
        int v = (i < n) ? cnt[i] : 0;
        __syncthreads();
        sdata[tid] = v;
        __syncthreads();
        for (int off = 1; off < 1024; off <<= 1) {
            int t = (tid >= off) ? sdata[tid - off] : 0;
            __syncthreads();
            sdata[tid] += t;
            __syncthreads();
        }
        int incl = sdata[tid];
        int excl = incl - v;
        int carry = s_carry;
        if (i < n) {
            int rs = carry + excl;
            row_start[i] = rs;
            cursor[i] = rs;
            inv_cnt[i] = 1.0f / fmaxf((float)v, 1.0f);
        }
        __syncthreads();
        if (tid == 1023) s_carry = carry + incl;
        __syncthreads();
    }
    if (tid == 0) row_start[n] = s_carry;
}

__global__ void scatter_kernel(const int* __restrict__ recv,
                               int* __restrict__ cursor,
                               int* __restrict__ edge_list) {
    int i = blockIdx.x * blockDim.x + threadIdx.x;
    if (i < N_EDGES) {
        int pos = atomicAdd(&cursor[recv[i]], 1);
        edge_list[pos] = i;
    }
}

// ---------------- per-step edge update ----------------
// thread = 4 edges x 16 features; lane pairs (tid^1) split the 32 features.
// block = 256 threads -> 128 groups -> 512 edges.

__global__ __launch_bounds__(256) void edge_kernel(
    float* __restrict__ e,            // [E][32] in/out
    const float* __restrict__ h,      // [N][32]
    const int* __restrict__ senders,
    const int* __restrict__ receivers,
    const float* __restrict__ W,      // [96][32]
    const float* __restrict__ bias,   // [32]
    const float* __restrict__ ln_s,   // [32]
    const float* __restrict__ ln_b) { // [32]
    __shared__ __align__(16) float Ws[96 * 32];
    __shared__ __align__(16) float prm[96];
    int tid = threadIdx.x;
    {
        const float4* Wg = (const float4*)W;
        float4* Wl = (float4*)Ws;
#pragma unroll
        for (int r = 0; r < 3; r++) Wl[tid + r * 256] = Wg[tid + r * 256];
        if (tid < 32) {
            prm[tid] = bias[tid];
            prm[32 + tid] = ln_s[tid];
            prm[64 + tid] = ln_b[tid];
        }
    }
    __syncthreads();
    int fh = tid & 1;                       // feature half: 0 -> f[0:16), 1 -> f[16:32)
    int g = blockIdx.x * 128 + (tid >> 1);  // 4-edge group
    if (g >= N_EDGES / 4) return;
    int e0 = g * 4;
    int sidx[4], ridx[4];
#pragma unroll
    for (int t = 0; t < 4; t++) {
        sidx[t] = senders[e0 + t];
        ridx[t] = receivers[e0 + t];
    }
    float4 acc[4][4];
#pragma unroll
    for (int t = 0; t < 4; t++)
#pragma unroll
        for (int q = 0; q < 4; q++)
            acc[t][q] = *(const float4*)&prm[fh * 16 + q * 4];

#pragma unroll
    for (int p = 0; p < 3; p++) {
        const float* base[4];
#pragma unroll
        for (int t = 0; t < 4; t++) {
            base[t] = (p == 0) ? (e + (size_t)(e0 + t) * 32)
                    : (p == 1) ? (h + (size_t)sidx[t] * 32)
                               : (h + (size_t)ridx[t] * 32);
        }
#pragma unroll 2
        for (int kc = 0; kc < 8; kc++) {
            float4 u[4];
#pragma unroll
            for (int t = 0; t < 4; t++) u[t] = *(const float4*)(base[t] + kc * 4);
#pragma unroll
            for (int j = 0; j < 4; j++) {
                int k = p * 32 + kc * 4 + j;
                float4 w[4];
#pragma unroll
                for (int q = 0; q < 4; q++)
                    w[q] = *(const float4*)&Ws[k * 32 + fh * 16 + q * 4];
#pragma unroll
                for (int t = 0; t < 4; t++) {
                    float uv = (j == 0) ? u[t].x : (j == 1) ? u[t].y : (j == 2) ? u[t].z : u[t].w;
#pragma unroll
                    for (int q = 0; q < 4; q++) acc[t][q] = f4fma(uv, w[q], acc[t][q]);
                }
            }
        }
    }

    // epilogue: leaky -> LN over 32 (pairwise via shfl_xor) -> *scale+bias -> residual
#pragma unroll
    for (int t = 0; t < 4; t++) {
        float m[16];
#pragma unroll
        for (int q = 0; q < 4; q++) {
            m[q * 4 + 0] = leaky(acc[t][q].x);
            m[q * 4 + 1] = leaky(acc[t][q].y);
            m[q * 4 + 2] = leaky(acc[t][q].z);
            m[q * 4 + 3] = leaky(acc[t][q].w);
        }
        float s1 = 0.0f, s2 = 0.0f;
#pragma unroll
        for (int i = 0; i < 16; i++) { s1 += m[i]; s2 += m[i] * m[i]; }
        s1 += __shfl_xor(s1, 1);
        s2 += __shfl_xor(s2, 1);
        float mu = s1 * (1.0f / 32.0f);
        float var = s2 * (1.0f / 32.0f) - mu * mu;
        float inv = rsqrtf(fmaxf(var, 0.0f) + LN_EPS);
        float* ep = e + (size_t)(e0 + t) * 32 + fh * 16;
#pragma unroll
        for (int q = 0; q < 4; q++) {
            float4 oldv = *(const float4*)(ep + q * 4);
            float4 sc = *(const float4*)&prm[32 + fh * 16 + q * 4];
            float4 bi = *(const float4*)&prm[64 + fh * 16 + q * 4];
            float4 res;
            res.x = oldv.x + (m[q * 4 + 0] - mu) * inv * sc.x + bi.x;
            res.y = oldv.y + (m[q * 4 + 1] - mu) * inv * sc.y + bi.y;
            res.z = oldv.z + (m[q * 4 + 2] - mu) * inv * sc.z + bi.z;
            res.w = oldv.w + (m[q * 4 + 3] - mu) * inv * sc.w + bi.w;
            *(float4*)(ep + q * 4) = res;
        }
    }
}

// ---------------- per-step node update ----------------

__global__ void agg_kernel(const float* __restrict__ e,
                           const int* __restrict__ row_start,
                           const int* __restrict__ edge_list,
                           const float* __restrict__ inv_cnt,
                           float* __restrict__ agg) {
    int i = blockIdx.x * blockDim.x + threadIdx.x;
    if (i >= N_NODES * 8) return;
    int n = i >> 3, q = i & 7;
    int beg = row_start[n], end = row_start[n + 1];
    float4 s = {0.0f, 0.0f, 0.0f, 0.0f};
    for (int j = beg; j < end; j++) {
        int idx = edge_list[j];
        float4 v = *(const float4*)&e[(size_t)idx * 32 + q * 4];
        s.x += v.x; s.y += v.y; s.z += v.z; s.w += v.w;
    }
    float ic = inv_cnt[n];
    s.x *= ic; s.y *= ic; s.z *= ic; s.w *= ic;
    *(float4*)&agg[(size_t)n * 32 + q * 4] = s;
}

__global__ void node_kernel(float* __restrict__ h,
                            const float* __restrict__ agg,
                            const float* __restrict__ W,     // [64][32]
                            const float* __restrict__ bias,  // [32]
                            const float* __restrict__ ln_s,
                            const float* __restrict__ ln_b) {
    __shared__ __align__(16) float Ws[64 * 32];
    __shared__ __align__(16) float prm[96];
    int tid = threadIdx.x;
    {
        const float4* Wg = (const float4*)W;
        float4* Wl = (float4*)Ws;
#pragma unroll
        for (int r = 0; r < 2; r++) Wl[tid + r * 256] = Wg[tid + r * 256];
        if (tid < 32) {
            prm[tid] = bias[tid];
            prm[32 + tid] = ln_s[tid];
            prm[64 + tid] = ln_b[tid];
        }
    }
    __syncthreads();
    int n = blockIdx.x * blockDim.x + tid;
    if (n >= N_NODES) return;
    float c[64];
#pragma unroll
    for (int q = 0; q < 8; q++) {
        float4 v = *(const float4*)&h[(size_t)n * 32 + q * 4];
        c[q * 4 + 0] = v.x; c[q * 4 + 1] = v.y; c[q * 4 + 2] = v.z; c[q * 4 + 3] = v.w;
    }
#pragma unroll
    for (int q = 0; q < 8; q++) {
        float4 v = *(const float4*)&agg[(size_t)n * 32 + q * 4];
        c[32 + q * 4 + 0] = v.x; c[32 + q * 4 + 1] = v.y; c[32 + q * 4 + 2] = v.z; c[32 + q * 4 + 3] = v.w;
    }
    float4 acc[8];
#pragma unroll
    for (int q = 0; q < 8; q++) acc[q] = *(const float4*)&prm[q * 4];
#pragma unroll
    for (int k = 0; k < 64; k++) {
#pragma unroll
        for (int q = 0; q < 8; q++) {
            float4 w = *(const float4*)&Ws[k * 32 + q * 4];
            acc[q] = f4fma(c[k], w, acc[q]);
        }
    }
    float m[32];
#pragma unroll
    for (int q = 0; q < 8; q++) {
        m[q * 4 + 0] = leaky(acc[q].x);
        m[q * 4 + 1] = leaky(acc[q].y);
        m[q * 4 + 2] = leaky(acc[q].z);
        m[q * 4 + 3] = leaky(acc[q].w);
    }
    float s1 = 0.0f, s2 = 0.0f;
#pragma unroll
    for (int i = 0; i < 32; i++) { s1 += m[i]; s2 += m[i] * m[i]; }
    float mu = s1 * (1.0f / 32.0f);
    float var = s2 * (1.0f / 32.0f) - mu * mu;
    float inv = rsqrtf(fmaxf(var, 0.0f) + LN_EPS);
#pragma unroll
    for (int q = 0; q < 8; q++) {
        float4 sc = *(const float4*)&prm[32 + q * 4];
        float4 bi = *(const float4*)&prm[64 + q * 4];
        float4 res;
        res.x = c[q * 4 + 0] + (m[q * 4 + 0] - mu) * inv * sc.x + bi.x;
        res.y = c[q * 4 + 1] + (m[q * 4 + 1] - mu) * inv * sc.y + bi.y;
        res.z = c[q * 4 + 2] + (m[q * 4 + 2] - mu) * inv * sc.z + bi.z;
        res.w = c[q * 4 + 3] + (m[q * 4 + 3] - mu) * inv * sc.w + bi.w;
        *(float4*)&h[(size_t)n * 32 + q * 4] = res;
    }
}

// ---------------- decoder ----------------

__global__ void decoder_kernel(const float* __restrict__ h,
                               const float* __restrict__ W1,  // [32][32]
                               const float* __restrict__ b1,  // [32]
                               const float* __restrict__ W2,  // [32][1]
                               const float* __restrict__ b2,  // [1]
                               float* __restrict__ out) {
    __shared__ __align__(16) float W1s[32 * 32];
    __shared__ __align__(16) float prm[65];
    int tid = threadIdx.x;
    {
        const float4* Wg = (const float4*)W1;
        float4* Wl = (float4*)W1s;
        Wl[tid] = Wg[tid];
        if (tid < 32) { prm[tid] = b1[tid]; prm[32 + tid] = W2[tid]; }
        if (tid == 0) prm[64] = b2[0];
    }
    __syncthreads();
    int n = blockIdx.x * blockDim.x + tid;
    if (n >= N_NODES) return;
    float hv[32];
#pragma unroll
    for (int q = 0; q < 8; q++) {
        float4 v = *(const float4*)&h[(size_t)n * 32 + q * 4];
        hv[q * 4 + 0] = v.x; hv[q * 4 + 1] = v.y; hv[q * 4 + 2] = v.z; hv[q * 4 + 3] = v.w;
    }
    float4 acc[8];
#pragma unroll
    for (int q = 0; q < 8; q++) acc[q] = *(const float4*)&prm[q * 4];
#pragma unroll
    for (int k = 0; k < 32; k++) {
#pragma unroll
        for (int q = 0; q < 8; q++) {
            float4 w = *(const float4*)&W1s[k * 32 + q * 4];
            acc[q] = f4fma(hv[k], w, acc[q]);
        }
    }
    float o = prm[64];
#pragma unroll
    for (int q = 0; q < 8; q++) {
        o += leaky(acc[q].x) * prm[32 + q * 4 + 0];
        o += leaky(acc[q].y) * prm[32 + q * 4 + 1];
        o += leaky(acc[q].z) * prm[32 + q * 4 + 2];
        o += leaky(acc[q].w) * prm[32 + q * 4 + 3];
    }
    out[n] = o;
}

// ---------------- launch ----------------

extern "C" void kernel_launch(void* const* d_in, const int* in_sizes, int n_in,
                              void* d_out, int out_size, void* d_ws, size_t ws_size,
                              hipStream_t stream) {
    const float* x          = (const float*)d_in[0];
    const float* edge_attr  = (const float*)d_in[1];
    const int*   senders    = (const int*)d_in[2];
    const int*   receivers  = (const int*)d_in[3];
    const float* node_enc_W = (const float*)d_in[4];
    const float* node_enc_b = (const float*)d_in[5];
    const float* edge_enc_W = (const float*)d_in[6];
    const float* edge_enc_b = (const float*)d_in[7];
    const float* edge_W     = (const float*)d_in[8];
    const float* edge_b     = (const float*)d_in[9];
    const float* edge_ln_s  = (const float*)d_in[10];
    const float* edge_ln_b  = (const float*)d_in[11];
    const float* node_W     = (const float*)d_in[12];
    const float* node_b     = (const float*)d_in[13];
    const float* node_ln_s  = (const float*)d_in[14];
    const float* node_ln_b  = (const float*)d_in[15];
    const float* dec_W1     = (const float*)d_in[16];
    const float* dec_b1     = (const float*)d_in[17];
    const float* dec_W2     = (const float*)d_in[18];
    const float* dec_b2     = (const float*)d_in[19];
    float* out = (float*)d_out;

    char* ws = (char*)d_ws;
    size_t off = 0;
    auto alloc = [&](size_t bytes) -> void* {
        void* p = ws + off;
        off = (off + bytes + 255) & ~(size_t)255;
        return p;
    };
    float* h         = (float*)alloc((size_t)N_NODES * 32 * 4);
    float* e         = (float*)alloc((size_t)N_EDGES * 32 * 4);
    float* agg       = (float*)alloc((size_t)N_NODES * 32 * 4);
    float* inv_cnt   = (float*)alloc((size_t)N_NODES * 4);
    int*   cnt       = (int*)alloc((size_t)N_NODES * 4);
    int*   row_start = (int*)alloc((size_t)(N_NODES + 1) * 4);
    int*   cursor    = (int*)alloc((size_t)N_NODES * 4);
    int*   edge_list = (int*)alloc((size_t)N_EDGES * 4);
    (void)ws_size; (void)in_sizes; (void)n_in; (void)out_size;

    hipMemsetAsync(cnt, 0, (size_t)N_NODES * 4, stream);
    encode_nodes_kernel<<<(N_NODES + 255) / 256, 256, 0, stream>>>(x, node_enc_W, node_enc_b, h);
    encode_edges_kernel<<<(N_EDGES + 255) / 256, 256, 0, stream>>>(edge_attr, edge_enc_W, edge_enc_b, e);
    count_kernel<<<(N_EDGES + 255) / 256, 256, 0, stream>>>(receivers, cnt);
    scan_kernel<<<1, 1024, 0, stream>>>(cnt, row_start, cursor, inv_cnt, N_NODES);
    scatter_kernel<<<(N_EDGES + 255) / 256, 256, 0, stream>>>(receivers, cursor, edge_list);

    for (int s = 0; s < STEPS; s++) {
        edge_kernel<<<(N_EDGES / 4 + 127) / 128, 256, 0, stream>>>(
            e, h, senders, receivers,
            edge_W + (size_t)s * 96 * 32, edge_b + s * 32,
            edge_ln_s + s * 32, edge_ln_b + s * 32);
        agg_kernel<<<(N_NODES * 8 + 255) / 256, 256, 0, stream>>>(e, row_start, edge_list, inv_cnt, agg);
        node_kernel<<<(N_NODES + 255) / 256, 256, 0, stream>>>(
            h, agg, node_W + (size_t)s * 64 * 32, node_b + s * 32,
            node_ln_s + s * 32, node_ln_b + s * 32);
    }
    decoder_kernel<<<(N_NODES + 255) / 256, 256, 0, stream>>>(h, dec_W1, dec_b1, dec_W2, dec_b2, out);
}

// Round 2
// 2087.903 us; speedup vs baseline: 1.1365x; 1.1365x over previous
//
#include <hip/hip_runtime.h>

#define N_NODES 50000
#define N_EDGES 800000
#define LATENT 32
#define STEPS 10
#define NEG_SLOPE 0.01f
#define LN_EPS 1e-5f

__device__ __forceinline__ float leaky(float x) {
    return x >= 0.0f ? x : NEG_SLOPE * x;
}

__device__ __forceinline__ float4 f4fma(float a, float4 b, float4 c) {
    c.x += a * b.x; c.y += a * b.y; c.z += a * b.z; c.w += a * b.w;
    return c;
}

// ---------------- encoders ----------------

__global__ void encode_nodes_kernel(const float* __restrict__ x,
                                    const float* __restrict__ W,  // [6][32]
                                    const float* __restrict__ b,  // [32]
                                    float* __restrict__ h) {
    __shared__ __align__(16) float Ws[6 * 32];
    __shared__ __align__(16) float bs[32];
    int tid = threadIdx.x;
    if (tid < 192) Ws[tid] = W[tid];
    if (tid < 32) bs[tid] = b[tid];
    __syncthreads();
    int n = blockIdx.x * blockDim.x + tid;
    if (n >= N_NODES) return;
    float xv[6];
#pragma unroll
    for (int k = 0; k < 6; k++) xv[k] = x[(size_t)n * 6 + k];
    float4 acc[8];
#pragma unroll
    for (int q = 0; q < 8; q++) acc[q] = *(const float4*)&bs[q * 4];
#pragma unroll
    for (int k = 0; k < 6; k++) {
#pragma unroll
        for (int q = 0; q < 8; q++) {
            float4 w = *(const float4*)&Ws[k * 32 + q * 4];
            acc[q] = f4fma(xv[k], w, acc[q]);
        }
    }
#pragma unroll
    for (int q = 0; q < 8; q++) {
        float4 o = acc[q];
        o.x = leaky(o.x); o.y = leaky(o.y); o.z = leaky(o.z); o.w = leaky(o.w);
        *(float4*)&h[(size_t)n * 32 + q * 4] = o;
    }
}

// encode edges in receiver-sorted (CSR-permuted) order: e[j] = enc(ea[edge_list[j]])
__global__ void encode_edges_kernel(const float* __restrict__ ea,
                                    const int* __restrict__ edge_list,
                                    const float* __restrict__ W,  // [3][32]
                                    const float* __restrict__ b,  // [32]
                                    float* __restrict__ e) {
    __shared__ __align__(16) float Ws[3 * 32];
    __shared__ __align__(16) float bs[32];
    int tid = threadIdx.x;
    if (tid < 96) Ws[tid] = W[tid];
    if (tid < 32) bs[tid] = b[tid];
    __syncthreads();
    int j = blockIdx.x * blockDim.x + tid;
    if (j >= N_EDGES) return;
    int i = edge_list[j];
    float xv[3];
#pragma unroll
    for (int k = 0; k < 3; k++) xv[k] = ea[(size_t)i * 3 + k];
    float4 acc[8];
#pragma unroll
    for (int q = 0; q < 8; q++) acc[q] = *(const float4*)&bs[q * 4];
#pragma unroll
    for (int k = 0; k < 3; k++) {
#pragma unroll
        for (int q = 0; q < 8; q++) {
            float4 w = *(const float4*)&Ws[k * 32 + q * 4];
            acc[q] = f4fma(xv[k], w, acc[q]);
        }
    }
#pragma unroll
    for (int q = 0; q < 8; q++) {
        float4 o = acc[q];
        o.x = leaky(o.x); o.y = leaky(o.y); o.z = leaky(o.z); o.w = leaky(o.w);
        *(float4*)&e[(size_t)j * 32 + q * 4] = o;
    }
}

// ---------------- CSR build (once per launch) ----------------

__global__ void count_kernel(const int* __restrict__ recv, int* __restrict__ cnt) {
    int i = blockIdx.x * blockDim.x + threadIdx.x;
    if (i < N_EDGES) atomicAdd(&cnt[recv[i]], 1);
}

__global__ void scan_kernel(const int* __restrict__ cnt,
                            int* __restrict__ row_start,
                            int* __restrict__ cursor,
                            float* __restrict__ inv_cnt, int n) {
    __shared__ int sdata[1024];
    __shared__ int s_carry;
    int tid = threadIdx.x;
    if (tid == 0) s_carry = 0;
    __syncthreads();
    for (int base = 0; base < n; base += 1024) {
        int i = base + tid;
        int v = (i < n) ? cnt[i] : 0;
        __syncthreads();
        sdata[tid] = v;
        __syncthreads();
        for (int off = 1; off < 1024; off <<= 1) {
            int t = (tid >= off) ? sdata[tid - off] : 0;
            __syncthreads();
            sdata[tid] += t;
            __syncthreads();
        }
        int incl = sdata[tid];
        int excl = incl - v;
        int carry = s_carry;
        if (i < n) {
            int rs = carry + excl;
            row_start[i] = rs;
            cursor[i] = rs;
            inv_cnt[i] = 1.0f / fmaxf((float)v, 1.0f);
        }
        __syncthreads();
        if (tid == 1023) s_carry = carry + incl;
        __syncthreads();
    }
    if (tid == 0) row_start[n] = s_carry;
}

__global__ void scatter_kernel(const int* __restrict__ recv,
                               int* __restrict__ cursor,
                               int* __restrict__ edge_list) {
    int i = blockIdx.x * blockDim.x + threadIdx.x;
    if (i < N_EDGES) {
        int pos = atomicAdd(&cursor[recv[i]], 1);
        edge_list[pos] = i;
    }
}

__global__ void permute_kernel(const int* __restrict__ senders,
                               const int* __restrict__ receivers,
                               const int* __restrict__ edge_list,
                               int* __restrict__ senders_p,
                               int* __restrict__ receivers_p) {
    int j = blockIdx.x * blockDim.x + threadIdx.x;
    if (j < N_EDGES) {
        int i = edge_list[j];
        senders_p[j] = senders[i];
        receivers_p[j] = receivers[i];
    }
}

// ---------------- per-step edge update ----------------
// thread = 4 edges x 16 features; lane pairs (tid^1) split the 32 features.
// edges are receiver-sorted -> h[recv] rows are block-local (L1 hits).
// Software-pipelined: chunk c+1's inputs load while chunk c's FMAs run.

__global__ __launch_bounds__(256) void edge_kernel(
    float* __restrict__ e,            // [E][32] in/out (receiver-sorted order)
    const float* __restrict__ h,      // [N][32]
    const int* __restrict__ senders,
    const int* __restrict__ receivers,
    const float* __restrict__ W,      // [96][32]
    const float* __restrict__ bias,   // [32]
    const float* __restrict__ ln_s,   // [32]
    const float* __restrict__ ln_b) { // [32]
    __shared__ __align__(16) float Ws[96 * 32];
    __shared__ __align__(16) float prm[96];
    int tid = threadIdx.x;
    {
        const float4* Wg = (const float4*)W;
        float4* Wl = (float4*)Ws;
#pragma unroll
        for (int r = 0; r < 3; r++) Wl[tid + r * 256] = Wg[tid + r * 256];
        if (tid < 32) {
            prm[tid] = bias[tid];
            prm[32 + tid] = ln_s[tid];
            prm[64 + tid] = ln_b[tid];
        }
    }
    __syncthreads();
    int fh = tid & 1;                       // feature half: 0 -> f[0:16), 1 -> f[16:32)
    int g = blockIdx.x * 128 + (tid >> 1);  // 4-edge group
    if (g >= N_EDGES / 4) return;
    int e0 = g * 4;

    // row offsets (in floats) for the 12 input rows: 4x e, 4x h_src, 4x h_dst
    int off_e[4], off_s[4], off_r[4];
#pragma unroll
    for (int t = 0; t < 4; t++) {
        off_e[t] = (e0 + t) * 32;
        off_s[t] = senders[e0 + t] * 32;
        off_r[t] = receivers[e0 + t] * 32;
    }

    float4 acc[4][4];
#pragma unroll
    for (int t = 0; t < 4; t++)
#pragma unroll
        for (int q = 0; q < 4; q++)
            acc[t][q] = *(const float4*)&prm[fh * 16 + q * 4];

    // chunk c in [0,24): phase p = c>>3 (0:e, 1:h_src, 2:h_dst), kc = c&7
    float4 u[4];
#pragma unroll
    for (int t = 0; t < 4; t++) u[t] = *(const float4*)&e[off_e[t]];

#pragma unroll
    for (int c = 0; c < 24; c++) {
        float4 un[4];
        if (c < 23) {
            const int cn = c + 1;
            const int pn = cn >> 3, kcn = cn & 7;
#pragma unroll
            for (int t = 0; t < 4; t++) {
                const float* base = (pn == 0) ? e : h;
                int off = (pn == 0) ? off_e[t] : (pn == 1) ? off_s[t] : off_r[t];
                un[t] = *(const float4*)&base[off + kcn * 4];
            }
        }
#pragma unroll
        for (int j = 0; j < 4; j++) {
            const int k = c * 4 + j;
            float4 w[4];
#pragma unroll
            for (int q = 0; q < 4; q++)
                w[q] = *(const float4*)&Ws[k * 32 + fh * 16 + q * 4];
#pragma unroll
            for (int t = 0; t < 4; t++) {
                float uv = (j == 0) ? u[t].x : (j == 1) ? u[t].y : (j == 2) ? u[t].z : u[t].w;
#pragma unroll
                for (int q = 0; q < 4; q++) acc[t][q] = f4fma(uv, w[q], acc[t][q]);
            }
        }
        if (c < 23) {
#pragma unroll
            for (int t = 0; t < 4; t++) u[t] = un[t];
        }
    }

    // prefetch residual e-rows (own half) before the LN math
    float4 res[4][4];
#pragma unroll
    for (int t = 0; t < 4; t++)
#pragma unroll
        for (int q = 0; q < 4; q++)
            res[t][q] = *(const float4*)&e[off_e[t] + fh * 16 + q * 4];

    // epilogue: leaky -> LN over 32 (pairwise via shfl_xor) -> *scale+bias -> residual
#pragma unroll
    for (int t = 0; t < 4; t++) {
        float m[16];
#pragma unroll
        for (int q = 0; q < 4; q++) {
            m[q * 4 + 0] = leaky(acc[t][q].x);
            m[q * 4 + 1] = leaky(acc[t][q].y);
            m[q * 4 + 2] = leaky(acc[t][q].z);
            m[q * 4 + 3] = leaky(acc[t][q].w);
        }
        float s1 = 0.0f, s2 = 0.0f;
#pragma unroll
        for (int i = 0; i < 16; i++) { s1 += m[i]; s2 += m[i] * m[i]; }
        s1 += __shfl_xor(s1, 1);
        s2 += __shfl_xor(s2, 1);
        float mu = s1 * (1.0f / 32.0f);
        float var = s2 * (1.0f / 32.0f) - mu * mu;
        float inv = rsqrtf(fmaxf(var, 0.0f) + LN_EPS);
        float* ep = e + (size_t)off_e[t] + fh * 16;
#pragma unroll
        for (int q = 0; q < 4; q++) {
            float4 sc = *(const float4*)&prm[32 + fh * 16 + q * 4];
            float4 bi = *(const float4*)&prm[64 + fh * 16 + q * 4];
            float4 r;
            r.x = res[t][q].x + (m[q * 4 + 0] - mu) * inv * sc.x + bi.x;
            r.y = res[t][q].y + (m[q * 4 + 1] - mu) * inv * sc.y + bi.y;
            r.z = res[t][q].z + (m[q * 4 + 2] - mu) * inv * sc.z + bi.z;
            r.w = res[t][q].w + (m[q * 4 + 3] - mu) * inv * sc.w + bi.w;
            *(float4*)(ep + q * 4) = r;
        }
    }
}

// ---------------- per-step node update ----------------
// e is receiver-sorted: node n's messages are rows [row_start[n], row_start[n+1])
// -> contiguous, coalesced segment sum.

__global__ void agg_kernel(const float* __restrict__ e,
                           const int* __restrict__ row_start,
                           const float* __restrict__ inv_cnt,
                           float* __restrict__ agg) {
    int i = blockIdx.x * blockDim.x + threadIdx.x;
    if (i >= N_NODES * 8) return;
    int n = i >> 3, q = i & 7;
    int beg = row_start[n], end = row_start[n + 1];
    float4 s = {0.0f, 0.0f, 0.0f, 0.0f};
    for (int j = beg; j < end; j++) {
        float4 v = *(const float4*)&e[(size_t)j * 32 + q * 4];
        s.x += v.x; s.y += v.y; s.z += v.z; s.w += v.w;
    }
    float ic = inv_cnt[n];
    s.x *= ic; s.y *= ic; s.z *= ic; s.w *= ic;
    *(float4*)&agg[(size_t)n * 32 + q * 4] = s;
}

__global__ void node_kernel(float* __restrict__ h,
                            const float* __restrict__ agg,
                            const float* __restrict__ W,     // [64][32]
                            const float* __restrict__ bias,  // [32]
                            const float* __restrict__ ln_s,
                            const float* __restrict__ ln_b) {
    __shared__ __align__(16) float Ws[64 * 32];
    __shared__ __align__(16) float prm[96];
    int tid = threadIdx.x;
    {
        const float4* Wg = (const float4*)W;
        float4* Wl = (float4*)Ws;
#pragma unroll
        for (int r = 0; r < 2; r++) Wl[tid + r * 256] = Wg[tid + r * 256];
        if (tid < 32) {
            prm[tid] = bias[tid];
            prm[32 + tid] = ln_s[tid];
            prm[64 + tid] = ln_b[tid];
        }
    }
    __syncthreads();
    int n = blockIdx.x * blockDim.x + tid;
    if (n >= N_NODES) return;
    float c[64];
#pragma unroll
    for (int q = 0; q < 8; q++) {
        float4 v = *(const float4*)&h[(size_t)n * 32 + q * 4];
        c[q * 4 + 0] = v.x; c[q * 4 + 1] = v.y; c[q * 4 + 2] = v.z; c[q * 4 + 3] = v.w;
    }
#pragma unroll
    for (int q = 0; q < 8; q++) {
        float4 v = *(const float4*)&agg[(size_t)n * 32 + q * 4];
        c[32 + q * 4 + 0] = v.x; c[32 + q * 4 + 1] = v.y; c[32 + q * 4 + 2] = v.z; c[32 + q * 4 + 3] = v.w;
    }
    float4 acc[8];
#pragma unroll
    for (int q = 0; q < 8; q++) acc[q] = *(const float4*)&prm[q * 4];
#pragma unroll
    for (int k = 0; k < 64; k++) {
#pragma unroll
        for (int q = 0; q < 8; q++) {
            float4 w = *(const float4*)&Ws[k * 32 + q * 4];
            acc[q] = f4fma(c[k], w, acc[q]);
        }
    }
    float m[32];
#pragma unroll
    for (int q = 0; q < 8; q++) {
        m[q * 4 + 0] = leaky(acc[q].x);
        m[q * 4 + 1] = leaky(acc[q].y);
        m[q * 4 + 2] = leaky(acc[q].z);
        m[q * 4 + 3] = leaky(acc[q].w);
    }
    float s1 = 0.0f, s2 = 0.0f;
#pragma unroll
    for (int i = 0; i < 32; i++) { s1 += m[i]; s2 += m[i] * m[i]; }
    float mu = s1 * (1.0f / 32.0f);
    float var = s2 * (1.0f / 32.0f) - mu * mu;
    float inv = rsqrtf(fmaxf(var, 0.0f) + LN_EPS);
#pragma unroll
    for (int q = 0; q < 8; q++) {
        float4 sc = *(const float4*)&prm[32 + q * 4];
        float4 bi = *(const float4*)&prm[64 + q * 4];
        float4 res;
        res.x = c[q * 4 + 0] + (m[q * 4 + 0] - mu) * inv * sc.x + bi.x;
        res.y = c[q * 4 + 1] + (m[q * 4 + 1] - mu) * inv * sc.y + bi.y;
        res.z = c[q * 4 + 2] + (m[q * 4 + 2] - mu) * inv * sc.z + bi.z;
        res.w = c[q * 4 + 3] + (m[q * 4 + 3] - mu) * inv * sc.w + bi.w;
        *(float4*)&h[(size_t)n * 32 + q * 4] = res;
    }
}

// ---------------- decoder ----------------

__global__ void decoder_kernel(const float* __restrict__ h,
                               const float* __restrict__ W1,  // [32][32]
                               const float* __restrict__ b1,  // [32]
                               const float* __restrict__ W2,  // [32][1]
                               const float* __restrict__ b2,  // [1]
                               float* __restrict__ out) {
    __shared__ __align__(16) float W1s[32 * 32];
    __shared__ __align__(16) float prm[65];
    int tid = threadIdx.x;
    {
        const float4* Wg = (const float4*)W1;
        float4* Wl = (float4*)W1s;
        Wl[tid] = Wg[tid];
        if (tid < 32) { prm[tid] = b1[tid]; prm[32 + tid] = W2[tid]; }
        if (tid == 0) prm[64] = b2[0];
    }
    __syncthreads();
    int n = blockIdx.x * blockDim.x + tid;
    if (n >= N_NODES) return;
    float hv[32];
#pragma unroll
    for (int q = 0; q < 8; q++) {
        float4 v = *(const float4*)&h[(size_t)n * 32 + q * 4];
        hv[q * 4 + 0] = v.x; hv[q * 4 + 1] = v.y; hv[q * 4 + 2] = v.z; hv[q * 4 + 3] = v.w;
    }
    float4 acc[8];
#pragma unroll
    for (int q = 0; q < 8; q++) acc[q] = *(const float4*)&prm[q * 4];
#pragma unroll
    for (int k = 0; k < 32; k++) {
#pragma unroll
        for (int q = 0; q < 8; q++) {
            float4 w = *(const float4*)&W1s[k * 32 + q * 4];
            acc[q] = f4fma(hv[k], w, acc[q]);
        }
    }
    float o = prm[64];
#pragma unroll
    for (int q = 0; q < 8; q++) {
        o += leaky(acc[q].x) * prm[32 + q * 4 + 0];
        o += leaky(acc[q].y) * prm[32 + q * 4 + 1];
        o += leaky(acc[q].z) * prm[32 + q * 4 + 2];
        o += leaky(acc[q].w) * prm[32 + q * 4 + 3];
    }
    out[n] = o;
}

// ---------------- launch ----------------

extern "C" void kernel_launch(void* const* d_in, const int* in_sizes, int n_in,
                              void* d_out, int out_size, void* d_ws, size_t ws_size,
                              hipStream_t stream) {
    const float* x          = (const float*)d_in[0];
    const float* edge_attr  = (const float*)d_in[1];
    const int*   senders    = (const int*)d_in[2];
    const int*   receivers  = (const int*)d_in[3];
    const float* node_enc_W = (const float*)d_in[4];
    const float* node_enc_b = (const float*)d_in[5];
    const float* edge_enc_W = (const float*)d_in[6];
    const float* edge_enc_b = (const float*)d_in[7];
    const float* edge_W     = (const float*)d_in[8];
    const float* edge_b     = (const float*)d_in[9];
    const float* edge_ln_s  = (const float*)d_in[10];
    const float* edge_ln_b  = (const float*)d_in[11];
    const float* node_W     = (const float*)d_in[12];
    const float* node_b     = (const float*)d_in[13];
    const float* node_ln_s  = (const float*)d_in[14];
    const float* node_ln_b  = (const float*)d_in[15];
    const float* dec_W1     = (const float*)d_in[16];
    const float* dec_b1     = (const float*)d_in[17];
    const float* dec_W2     = (const float*)d_in[18];
    const float* dec_b2     = (const float*)d_in[19];
    float* out = (float*)d_out;

    char* ws = (char*)d_ws;
    size_t off = 0;
    auto alloc = [&](size_t bytes) -> void* {
        void* p = ws + off;
        off = (off + bytes + 255) & ~(size_t)255;
        return p;
    };
    float* h          = (float*)alloc((size_t)N_NODES * 32 * 4);
    float* e          = (float*)alloc((size_t)N_EDGES * 32 * 4);
    float* agg        = (float*)alloc((size_t)N_NODES * 32 * 4);
    float* inv_cnt    = (float*)alloc((size_t)N_NODES * 4);
    int*   cnt        = (int*)alloc((size_t)N_NODES * 4);
    int*   row_start  = (int*)alloc((size_t)(N_NODES + 1) * 4);
    int*   cursor     = (int*)alloc((size_t)N_NODES * 4);
    int*   edge_list  = (int*)alloc((size_t)N_EDGES * 4);
    int*   senders_p  = (int*)alloc((size_t)N_EDGES * 4);
    int*   receivers_p= (int*)alloc((size_t)N_EDGES * 4);
    (void)ws_size; (void)in_sizes; (void)n_in; (void)out_size;

    hipMemsetAsync(cnt, 0, (size_t)N_NODES * 4, stream);
    encode_nodes_kernel<<<(N_NODES + 255) / 256, 256, 0, stream>>>(x, node_enc_W, node_enc_b, h);
    count_kernel<<<(N_EDGES + 255) / 256, 256, 0, stream>>>(receivers, cnt);
    scan_kernel<<<1, 1024, 0, stream>>>(cnt, row_start, cursor, inv_cnt, N_NODES);
    scatter_kernel<<<(N_EDGES + 255) / 256, 256, 0, stream>>>(receivers, cursor, edge_list);
    permute_kernel<<<(N_EDGES + 255) / 256, 256, 0, stream>>>(senders, receivers, edge_list,
                                                              senders_p, receivers_p);
    encode_edges_kernel<<<(N_EDGES + 255) / 256, 256, 0, stream>>>(edge_attr, edge_list,
                                                                   edge_enc_W, edge_enc_b, e);

    for (int s = 0; s < STEPS; s++) {
        edge_kernel<<<(N_EDGES / 4 + 127) / 128, 256, 0, stream>>>(
            e, h, senders_p, receivers_p,
            edge_W + (size_t)s * 96 * 32, edge_b + s * 32,
            edge_ln_s + s * 32, edge_ln_b + s * 32);
        agg_kernel<<<(N_NODES * 8 + 255) / 256, 256, 0, stream>>>(e, row_start, inv_cnt, agg);
        node_kernel<<<(N_NODES + 255) / 256, 256, 0, stream>>>(
            h, agg, node_W + (size_t)s * 64 * 32, node_b + s * 32,
            node_ln_s + s * 32, node_ln_b + s * 32);
    }
    decoder_kernel<<<(N_NODES + 255) / 256, 256, 0, stream>>>(h, dec_W1, dec_b1, dec_W2, dec_b2, out);
}

// Round 3
// 1382.789 us; speedup vs baseline: 1.7160x; 1.5099x over previous
//
#include <hip/hip_runtime.h>
#include <hip/hip_bf16.h>

#define N_NODES 50000
#define N_EDGES 800000
#define LATENT 32
#define STEPS 10
#define NEG_SLOPE 0.01f
#define LN_EPS 1e-5f
#define N_TILES (N_EDGES / 16)
#define TPW 8  // tiles per wave

typedef __attribute__((ext_vector_type(8))) __bf16 bf16x8;
typedef __attribute__((ext_vector_type(4))) float f32x4;

__device__ __forceinline__ float leaky(float x) {
    return x >= 0.0f ? x : NEG_SLOPE * x;
}

__device__ __forceinline__ float4 f4fma(float a, float4 b, float4 c) {
    c.x += a * b.x; c.y += a * b.y; c.z += a * b.z; c.w += a * b.w;
    return c;
}

__device__ __forceinline__ bf16x8 mkfrag8(const float* v) {
    bf16x8 f;
#pragma unroll
    for (int j = 0; j < 8; j++) f[j] = (__bf16)v[j];
    return f;
}

// ---------------- encoders ----------------

__global__ void encode_nodes_kernel(const float* __restrict__ x,
                                    const float* __restrict__ W,  // [6][32]
                                    const float* __restrict__ b,  // [32]
                                    float* __restrict__ h) {
    __shared__ __align__(16) float Ws[6 * 32];
    __shared__ __align__(16) float bs[32];
    int tid = threadIdx.x;
    if (tid < 192) Ws[tid] = W[tid];
    if (tid < 32) bs[tid] = b[tid];
    __syncthreads();
    int n = blockIdx.x * blockDim.x + tid;
    if (n >= N_NODES) return;
    float xv[6];
#pragma unroll
    for (int k = 0; k < 6; k++) xv[k] = x[(size_t)n * 6 + k];
    float4 acc[8];
#pragma unroll
    for (int q = 0; q < 8; q++) acc[q] = *(const float4*)&bs[q * 4];
#pragma unroll
    for (int k = 0; k < 6; k++) {
#pragma unroll
        for (int q = 0; q < 8; q++) {
            float4 w = *(const float4*)&Ws[k * 32 + q * 4];
            acc[q] = f4fma(xv[k], w, acc[q]);
        }
    }
#pragma unroll
    for (int q = 0; q < 8; q++) {
        float4 o = acc[q];
        o.x = leaky(o.x); o.y = leaky(o.y); o.z = leaky(o.z); o.w = leaky(o.w);
        *(float4*)&h[(size_t)n * 32 + q * 4] = o;
    }
}

// encode edges in receiver-sorted (CSR-permuted) order: e[j] = enc(ea[edge_list[j]])
__global__ void encode_edges_kernel(const float* __restrict__ ea,
                                    const int* __restrict__ edge_list,
                                    const float* __restrict__ W,  // [3][32]
                                    const float* __restrict__ b,  // [32]
                                    float* __restrict__ e) {
    __shared__ __align__(16) float Ws[3 * 32];
    __shared__ __align__(16) float bs[32];
    int tid = threadIdx.x;
    if (tid < 96) Ws[tid] = W[tid];
    if (tid < 32) bs[tid] = b[tid];
    __syncthreads();
    int j = blockIdx.x * blockDim.x + tid;
    if (j >= N_EDGES) return;
    int i = edge_list[j];
    float xv[3];
#pragma unroll
    for (int k = 0; k < 3; k++) xv[k] = ea[(size_t)i * 3 + k];
    float4 acc[8];
#pragma unroll
    for (int q = 0; q < 8; q++) acc[q] = *(const float4*)&bs[q * 4];
#pragma unroll
    for (int k = 0; k < 3; k++) {
#pragma unroll
        for (int q = 0; q < 8; q++) {
            float4 w = *(const float4*)&Ws[k * 32 + q * 4];
            acc[q] = f4fma(xv[k], w, acc[q]);
        }
    }
#pragma unroll
    for (int q = 0; q < 8; q++) {
        float4 o = acc[q];
        o.x = leaky(o.x); o.y = leaky(o.y); o.z = leaky(o.z); o.w = leaky(o.w);
        *(float4*)&e[(size_t)j * 32 + q * 4] = o;
    }
}

// ---------------- CSR build (once per launch) ----------------

__global__ void count_kernel(const int* __restrict__ recv, int* __restrict__ cnt) {
    int i = blockIdx.x * blockDim.x + threadIdx.x;
    if (i < N_EDGES) atomicAdd(&cnt[recv[i]], 1);
}

__global__ void scan_kernel(const int* __restrict__ cnt,
                            int* __restrict__ row_start,
                            int* __restrict__ cursor,
                            float* __restrict__ inv_cnt, int n) {
    __shared__ int sdata[1024];
    __shared__ int s_carry;
    int tid = threadIdx.x;
    if (tid == 0) s_carry = 0;
    __syncthreads();
    for (int base = 0; base < n; base += 1024) {
        int i = base + tid;
        int v = (i < n) ? cnt[i] : 0;
        __syncthreads();
        sdata[tid] = v;
        __syncthreads();
        for (int off = 1; off < 1024; off <<= 1) {
            int t = (tid >= off) ? sdata[tid - off] : 0;
            __syncthreads();
            sdata[tid] += t;
            __syncthreads();
        }
        int incl = sdata[tid];
        int excl = incl - v;
        int carry = s_carry;
        if (i < n) {
            int rs = carry + excl;
            row_start[i] = rs;
            cursor[i] = rs;
            inv_cnt[i] = 1.0f / fmaxf((float)v, 1.0f);
        }
        __syncthreads();
        if (tid == 1023) s_carry = carry + incl;
        __syncthreads();
    }
    if (tid == 0) row_start[n] = s_carry;
}

__global__ void scatter_kernel(const int* __restrict__ recv,
                               int* __restrict__ cursor,
                               int* __restrict__ edge_list) {
    int i = blockIdx.x * blockDim.x + threadIdx.x;
    if (i < N_EDGES) {
        int pos = atomicAdd(&cursor[recv[i]], 1);
        edge_list[pos] = i;
    }
}

__global__ void permute_kernel(const int* __restrict__ senders,
                               const int* __restrict__ receivers,
                               const int* __restrict__ edge_list,
                               int* __restrict__ senders_p,
                               int* __restrict__ receivers_p) {
    int j = blockIdx.x * blockDim.x + threadIdx.x;
    if (j < N_EDGES) {
        int i = edge_list[j];
        senders_p[j] = senders[i];
        receivers_p[j] = receivers[i];
    }
}

// ---------------- per-step edge update (MFMA) ----------------
// Wave computes 16-edge tiles with mfma_f32_16x16x32_bf16.
// A layout: lane holds A[m=lane&15][k=(lane>>4)*8+j]  (verified m120)
// B layout: lane holds B[k=(lane>>4)*8+j][n=lane&15]  (W fragment, in VGPRs)
// C/D layout: col=lane&15, row=(lane>>4)*4+reg        (verified m89)
// K = 96 in 3 chunks: e[k 0:32), h_src[32:64), h_dst[64:96).
// Residual + LN epilogue in fp32; e stays fp32 in memory.

__global__ __launch_bounds__(256) void edge_mfma_kernel(
    float* __restrict__ e,            // [E][32] in/out (receiver-sorted order)
    const float* __restrict__ h,      // [N][32]
    const int* __restrict__ senders,
    const int* __restrict__ receivers,
    const float* __restrict__ W,      // [96][32]
    const float* __restrict__ bias,   // [32]
    const float* __restrict__ ln_s,   // [32]
    const float* __restrict__ ln_b) { // [32]
    __shared__ __align__(16) float Ws[96 * 32];
    __shared__ __align__(16) float prm[96];
    int tid = threadIdx.x;
    {
        const float4* Wg = (const float4*)W;
        float4* Wl = (float4*)Ws;
#pragma unroll
        for (int r = 0; r < 3; r++) Wl[tid + r * 256] = Wg[tid + r * 256];
        if (tid < 32) {
            prm[tid] = bias[tid];
            prm[32 + tid] = ln_s[tid];
            prm[64 + tid] = ln_b[tid];
        }
    }
    __syncthreads();

    const int wave = tid >> 6;
    const int lane = tid & 63;
    const int n_ = lane & 15;
    const int quad = lane >> 4;

    // B fragments: bf[kc][oh], element j = W[kc*32 + quad*8 + j][oh*16 + n_]
    bf16x8 bf[3][2];
#pragma unroll
    for (int kc = 0; kc < 3; kc++)
#pragma unroll
        for (int oh = 0; oh < 2; oh++) {
            float v[8];
#pragma unroll
            for (int j = 0; j < 8; j++)
                v[j] = Ws[(kc * 32 + quad * 8 + j) * 32 + oh * 16 + n_];
            bf[kc][oh] = mkfrag8(v);
        }
    // epilogue params for this lane's two columns: n_ and n_+16
    float bia[2] = {prm[n_], prm[16 + n_]};
    float lns[2] = {prm[32 + n_], prm[48 + n_]};
    float lnb[2] = {prm[64 + n_], prm[80 + n_]};

    int tile0 = blockIdx.x * (4 * TPW) + wave * TPW;
    if (tile0 >= N_TILES) return;

    int s_cur = senders[tile0 * 16 + n_];
    int r_cur = receivers[tile0 * 16 + n_];

    for (int t = 0; t < TPW; t++) {
        int tile = tile0 + t;
        if (tile >= N_TILES) break;
        int e0 = tile * 16;
        int ed = e0 + n_;

        // A-operand raw loads (fp32): lane covers k = quad*8 .. quad*8+8
        const float* eb = e + (size_t)ed * 32 + quad * 8;
        const float* sb = h + (size_t)s_cur * 32 + quad * 8;
        const float* rb = h + (size_t)r_cur * 32 + quad * 8;
        float4 e4a = *(const float4*)eb;
        float4 e4b = *(const float4*)(eb + 4);
        float4 s4a = *(const float4*)sb;
        float4 s4b = *(const float4*)(sb + 4);
        float4 r4a = *(const float4*)rb;
        float4 r4b = *(const float4*)(rb + 4);

        // prefetch next tile's gather indices
        if (t + 1 < TPW && tile + 1 < N_TILES) {
            s_cur = senders[ed + 16];
            r_cur = receivers[ed + 16];
        }

        float vE[8] = {e4a.x, e4a.y, e4a.z, e4a.w, e4b.x, e4b.y, e4b.z, e4b.w};
        float vS[8] = {s4a.x, s4a.y, s4a.z, s4a.w, s4b.x, s4b.y, s4b.z, s4b.w};
        float vR[8] = {r4a.x, r4a.y, r4a.z, r4a.w, r4b.x, r4b.y, r4b.z, r4b.w};
        bf16x8 aE = mkfrag8(vE);
        bf16x8 aS = mkfrag8(vS);
        bf16x8 aR = mkfrag8(vR);

        f32x4 acc[2] = {{0.f, 0.f, 0.f, 0.f}, {0.f, 0.f, 0.f, 0.f}};
#pragma unroll
        for (int oh = 0; oh < 2; oh++) {
            acc[oh] = __builtin_amdgcn_mfma_f32_16x16x32_bf16(aE, bf[0][oh], acc[oh], 0, 0, 0);
            acc[oh] = __builtin_amdgcn_mfma_f32_16x16x32_bf16(aS, bf[1][oh], acc[oh], 0, 0, 0);
            acc[oh] = __builtin_amdgcn_mfma_f32_16x16x32_bf16(aR, bf[2][oh], acc[oh], 0, 0, 0);
        }

        // epilogue: lane holds D rows (quad*4+g), cols n_ + 16*oh
        float val[2][4];
#pragma unroll
        for (int oh = 0; oh < 2; oh++)
#pragma unroll
            for (int g = 0; g < 4; g++)
                val[oh][g] = leaky(acc[oh][g] + bia[oh]);

#pragma unroll
        for (int g = 0; g < 4; g++) {
            int er = e0 + quad * 4 + g;
            float s1 = val[0][g] + val[1][g];
            float s2 = val[0][g] * val[0][g] + val[1][g] * val[1][g];
            s1 += __shfl_xor(s1, 1);  s2 += __shfl_xor(s2, 1);
            s1 += __shfl_xor(s1, 2);  s2 += __shfl_xor(s2, 2);
            s1 += __shfl_xor(s1, 4);  s2 += __shfl_xor(s2, 4);
            s1 += __shfl_xor(s1, 8);  s2 += __shfl_xor(s2, 8);
            float mu = s1 * (1.0f / 32.0f);
            float var = s2 * (1.0f / 32.0f) - mu * mu;
            float inv = rsqrtf(fmaxf(var, 0.0f) + LN_EPS);
            float* ep = e + (size_t)er * 32 + n_;
            float o0 = ep[0]  + (val[0][g] - mu) * inv * lns[0] + lnb[0];
            float o1 = ep[16] + (val[1][g] - mu) * inv * lns[1] + lnb[1];
            ep[0] = o0;
            ep[16] = o1;
        }
    }
}

// ---------------- per-step node update ----------------

__global__ void agg_kernel(const float* __restrict__ e,
                           const int* __restrict__ row_start,
                           const float* __restrict__ inv_cnt,
                           float* __restrict__ agg) {
    int i = blockIdx.x * blockDim.x + threadIdx.x;
    if (i >= N_NODES * 8) return;
    int n = i >> 3, q = i & 7;
    int beg = row_start[n], end = row_start[n + 1];
    float4 s = {0.0f, 0.0f, 0.0f, 0.0f};
    for (int j = beg; j < end; j++) {
        float4 v = *(const float4*)&e[(size_t)j * 32 + q * 4];
        s.x += v.x; s.y += v.y; s.z += v.z; s.w += v.w;
    }
    float ic = inv_cnt[n];
    s.x *= ic; s.y *= ic; s.z *= ic; s.w *= ic;
    *(float4*)&agg[(size_t)n * 32 + q * 4] = s;
}

__global__ void node_kernel(float* __restrict__ h,
                            const float* __restrict__ agg,
                            const float* __restrict__ W,     // [64][32]
                            const float* __restrict__ bias,  // [32]
                            const float* __restrict__ ln_s,
                            const float* __restrict__ ln_b) {
    __shared__ __align__(16) float Ws[64 * 32];
    __shared__ __align__(16) float prm[96];
    int tid = threadIdx.x;
    {
        const float4* Wg = (const float4*)W;
        float4* Wl = (float4*)Ws;
#pragma unroll
        for (int r = 0; r < 2; r++) Wl[tid + r * 256] = Wg[tid + r * 256];
        if (tid < 32) {
            prm[tid] = bias[tid];
            prm[32 + tid] = ln_s[tid];
            prm[64 + tid] = ln_b[tid];
        }
    }
    __syncthreads();
    int n = blockIdx.x * blockDim.x + tid;
    if (n >= N_NODES) return;
    float c[64];
#pragma unroll
    for (int q = 0; q < 8; q++) {
        float4 v = *(const float4*)&h[(size_t)n * 32 + q * 4];
        c[q * 4 + 0] = v.x; c[q * 4 + 1] = v.y; c[q * 4 + 2] = v.z; c[q * 4 + 3] = v.w;
    }
#pragma unroll
    for (int q = 0; q < 8; q++) {
        float4 v = *(const float4*)&agg[(size_t)n * 32 + q * 4];
        c[32 + q * 4 + 0] = v.x; c[32 + q * 4 + 1] = v.y; c[32 + q * 4 + 2] = v.z; c[32 + q * 4 + 3] = v.w;
    }
    float4 acc[8];
#pragma unroll
    for (int q = 0; q < 8; q++) acc[q] = *(const float4*)&prm[q * 4];
#pragma unroll
    for (int k = 0; k < 64; k++) {
#pragma unroll
        for (int q = 0; q < 8; q++) {
            float4 w = *(const float4*)&Ws[k * 32 + q * 4];
            acc[q] = f4fma(c[k], w, acc[q]);
        }
    }
    float m[32];
#pragma unroll
    for (int q = 0; q < 8; q++) {
        m[q * 4 + 0] = leaky(acc[q].x);
        m[q * 4 + 1] = leaky(acc[q].y);
        m[q * 4 + 2] = leaky(acc[q].z);
        m[q * 4 + 3] = leaky(acc[q].w);
    }
    float s1 = 0.0f, s2 = 0.0f;
#pragma unroll
    for (int i = 0; i < 32; i++) { s1 += m[i]; s2 += m[i] * m[i]; }
    float mu = s1 * (1.0f / 32.0f);
    float var = s2 * (1.0f / 32.0f) - mu * mu;
    float inv = rsqrtf(fmaxf(var, 0.0f) + LN_EPS);
#pragma unroll
    for (int q = 0; q < 8; q++) {
        float4 sc = *(const float4*)&prm[32 + q * 4];
        float4 bi = *(const float4*)&prm[64 + q * 4];
        float4 res;
        res.x = c[q * 4 + 0] + (m[q * 4 + 0] - mu) * inv * sc.x + bi.x;
        res.y = c[q * 4 + 1] + (m[q * 4 + 1] - mu) * inv * sc.y + bi.y;
        res.z = c[q * 4 + 2] + (m[q * 4 + 2] - mu) * inv * sc.z + bi.z;
        res.w = c[q * 4 + 3] + (m[q * 4 + 3] - mu) * inv * sc.w + bi.w;
        *(float4*)&h[(size_t)n * 32 + q * 4] = res;
    }
}

// ---------------- decoder ----------------

__global__ void decoder_kernel(const float* __restrict__ h,
                               const float* __restrict__ W1,  // [32][32]
                               const float* __restrict__ b1,  // [32]
                               const float* __restrict__ W2,  // [32][1]
                               const float* __restrict__ b2,  // [1]
                               float* __restrict__ out) {
    __shared__ __align__(16) float W1s[32 * 32];
    __shared__ __align__(16) float prm[65];
    int tid = threadIdx.x;
    {
        const float4* Wg = (const float4*)W1;
        float4* Wl = (float4*)W1s;
        Wl[tid] = Wg[tid];
        if (tid < 32) { prm[tid] = b1[tid]; prm[32 + tid] = W2[tid]; }
        if (tid == 0) prm[64] = b2[0];
    }
    __syncthreads();
    int n = blockIdx.x * blockDim.x + tid;
    if (n >= N_NODES) return;
    float hv[32];
#pragma unroll
    for (int q = 0; q < 8; q++) {
        float4 v = *(const float4*)&h[(size_t)n * 32 + q * 4];
        hv[q * 4 + 0] = v.x; hv[q * 4 + 1] = v.y; hv[q * 4 + 2] = v.z; hv[q * 4 + 3] = v.w;
    }
    float4 acc[8];
#pragma unroll
    for (int q = 0; q < 8; q++) acc[q] = *(const float4*)&prm[q * 4];
#pragma unroll
    for (int k = 0; k < 32; k++) {
#pragma unroll
        for (int q = 0; q < 8; q++) {
            float4 w = *(const float4*)&W1s[k * 32 + q * 4];
            acc[q] = f4fma(hv[k], w, acc[q]);
        }
    }
    float o = prm[64];
#pragma unroll
    for (int q = 0; q < 8; q++) {
        o += leaky(acc[q].x) * prm[32 + q * 4 + 0];
        o += leaky(acc[q].y) * prm[32 + q * 4 + 1];
        o += leaky(acc[q].z) * prm[32 + q * 4 + 2];
        o += leaky(acc[q].w) * prm[32 + q * 4 + 3];
    }
    out[n] = o;
}

// ---------------- launch ----------------

extern "C" void kernel_launch(void* const* d_in, const int* in_sizes, int n_in,
                              void* d_out, int out_size, void* d_ws, size_t ws_size,
                              hipStream_t stream) {
    const float* x          = (const float*)d_in[0];
    const float* edge_attr  = (const float*)d_in[1];
    const int*   senders    = (const int*)d_in[2];
    const int*   receivers  = (const int*)d_in[3];
    const float* node_enc_W = (const float*)d_in[4];
    const float* node_enc_b = (const float*)d_in[5];
    const float* edge_enc_W = (const float*)d_in[6];
    const float* edge_enc_b = (const float*)d_in[7];
    const float* edge_W     = (const float*)d_in[8];
    const float* edge_b     = (const float*)d_in[9];
    const float* edge_ln_s  = (const float*)d_in[10];
    const float* edge_ln_b  = (const float*)d_in[11];
    const float* node_W     = (const float*)d_in[12];
    const float* node_b     = (const float*)d_in[13];
    const float* node_ln_s  = (const float*)d_in[14];
    const float* node_ln_b  = (const float*)d_in[15];
    const float* dec_W1     = (const float*)d_in[16];
    const float* dec_b1     = (const float*)d_in[17];
    const float* dec_W2     = (const float*)d_in[18];
    const float* dec_b2     = (const float*)d_in[19];
    float* out = (float*)d_out;

    char* ws = (char*)d_ws;
    size_t off = 0;
    auto alloc = [&](size_t bytes) -> void* {
        void* p = ws + off;
        off = (off + bytes + 255) & ~(size_t)255;
        return p;
    };
    float* h          = (float*)alloc((size_t)N_NODES * 32 * 4);
    float* e          = (float*)alloc((size_t)N_EDGES * 32 * 4);
    float* agg        = (float*)alloc((size_t)N_NODES * 32 * 4);
    float* inv_cnt    = (float*)alloc((size_t)N_NODES * 4);
    int*   cnt        = (int*)alloc((size_t)N_NODES * 4);
    int*   row_start  = (int*)alloc((size_t)(N_NODES + 1) * 4);
    int*   cursor     = (int*)alloc((size_t)N_NODES * 4);
    int*   edge_list  = (int*)alloc((size_t)N_EDGES * 4);
    int*   senders_p  = (int*)alloc((size_t)N_EDGES * 4);
    int*   receivers_p= (int*)alloc((size_t)N_EDGES * 4);
    (void)ws_size; (void)in_sizes; (void)n_in; (void)out_size;

    hipMemsetAsync(cnt, 0, (size_t)N_NODES * 4, stream);
    encode_nodes_kernel<<<(N_NODES + 255) / 256, 256, 0, stream>>>(x, node_enc_W, node_enc_b, h);
    count_kernel<<<(N_EDGES + 255) / 256, 256, 0, stream>>>(receivers, cnt);
    scan_kernel<<<1, 1024, 0, stream>>>(cnt, row_start, cursor, inv_cnt, N_NODES);
    scatter_kernel<<<(N_EDGES + 255) / 256, 256, 0, stream>>>(receivers, cursor, edge_list);
    permute_kernel<<<(N_EDGES + 255) / 256, 256, 0, stream>>>(senders, receivers, edge_list,
                                                              senders_p, receivers_p);
    encode_edges_kernel<<<(N_EDGES + 255) / 256, 256, 0, stream>>>(edge_attr, edge_list,
                                                                   edge_enc_W, edge_enc_b, e);

    int edge_blocks = (N_TILES + 4 * TPW - 1) / (4 * TPW);
    for (int s = 0; s < STEPS; s++) {
        edge_mfma_kernel<<<edge_blocks, 256, 0, stream>>>(
            e, h, senders_p, receivers_p,
            edge_W + (size_t)s * 96 * 32, edge_b + s * 32,
            edge_ln_s + s * 32, edge_ln_b + s * 32);
        agg_kernel<<<(N_NODES * 8 + 255) / 256, 256, 0, stream>>>(e, row_start, inv_cnt, agg);
        node_kernel<<<(N_NODES + 255) / 256, 256, 0, stream>>>(
            h, agg, node_W + (size_t)s * 64 * 32, node_b + s * 32,
            node_ln_s + s * 32, node_ln_b + s * 32);
    }
    decoder_kernel<<<(N_NODES + 255) / 256, 256, 0, stream>>>(h, dec_W1, dec_b1, dec_W2, dec_b2, out);
}